// Round 1
// baseline (1048.634 us; speedup 1.0000x reference)
//
#include <hip/hip_runtime.h>
#include <cstdint>

// GraphNets block, fp32 baseline.
// Fixed dims: DE=DN=DU=DO=64, H1=H2=128. K_edge=256, K_node=192, K_u=192.
constexpr int H = 128;   // hidden width
constexpr int TE = 64;   // rows (edges/nodes) per block tile

// ---------------------------------------------------------------------------
// Tiled 3-layer MLP over M rows. Input gathered per 64-wide k-chunk:
//   EDGE: [edge_feat | node_feat[src] | node_feat[dst] | g_repr[e2g]]  (4 chunks)
//   NODE: [node_feat | msgs           | g_repr[n2g]]                  (3 chunks)
// LDS arena: A 16KB (x-chunk / W2 / W3 chunks), B 32KB (W1 chunk, then h2T),
//            C 32KB (h1T). 80KB total -> 2 blocks/CU.
// Thread tile: 8 rows x 4 cols (layers 1-2), 8 rows x 2 cols (layer 3).
// ---------------------------------------------------------------------------
template <int NCHUNK, bool IS_EDGE>
__global__ __launch_bounds__(256, 2)
void mlp_tile_kernel(const float* __restrict__ feat0,  // edge_feat / node_feat
                     const float* feat1,               // node_feat / msgs (aliases out for NODE)
                     const float* __restrict__ gr,
                     const int* __restrict__ src,
                     const int* __restrict__ dst,
                     const int* __restrict__ seg,
                     const float* __restrict__ W1, const float* __restrict__ b1,
                     const float* __restrict__ W2, const float* __restrict__ b2,
                     const float* __restrict__ W3, const float* __restrict__ b3,
                     float* out,                       // e_out / n_out
                     float* msgs_out,                  // msgs accumulation (EDGE only)
                     int M)
{
    __shared__ float A[4096];   // 16 KB
    __shared__ float B[8192];   // 32 KB
    __shared__ float C[8192];   // 32 KB

    const int t  = threadIdx.x;
    const int jg = t & 31;       // 32 col-groups
    const int eg = t >> 5;       // 8 row-groups
    const int r0 = eg * 8;       // this thread's 8 local rows
    const int j0 = jg * 4;       // this thread's 4 cols (layers 1-2)
    const int base = blockIdx.x * TE;

    // ---- layer 1: acc[8 rows][4 cols], K = NCHUNK*64 ----
    float acc[8][4];
    {
        const float4 bb = *(const float4*)(b1 + j0);
#pragma unroll
        for (int ee = 0; ee < 8; ++ee) {
            acc[ee][0] = bb.x; acc[ee][1] = bb.y; acc[ee][2] = bb.z; acc[ee][3] = bb.w;
        }
    }

    for (int c = 0; c < NCHUNK; ++c) {
        __syncthreads();  // prior readers of A/B done
        // gather x chunk -> A[k][r]  (k local 0..63, r 0..63)
#pragma unroll
        for (int i = 0; i < 4; ++i) {
            const int c4 = i * 256 + t;      // 0..1023 float4 slots
            const int r  = c4 >> 4;          // 0..63
            const int k4 = c4 & 15;          // 0..15
            const int row = base + r;
            float4 v = make_float4(0.f, 0.f, 0.f, 0.f);
            if (row < M) {
                const float* p;
                if (IS_EDGE) {
                    if      (c == 0) p = feat0 + (size_t)row * 64;
                    else if (c == 1) p = feat1 + (size_t)src[row] * 64;
                    else if (c == 2) p = feat1 + (size_t)dst[row] * 64;
                    else             p = gr    + (size_t)seg[row] * 64;
                } else {
                    if      (c == 0) p = feat0 + (size_t)row * 64;
                    else if (c == 1) p = feat1 + (size_t)row * 64;
                    else             p = gr    + (size_t)seg[row] * 64;
                }
                v = *(const float4*)(p + k4 * 4);
            }
            A[(k4 * 4 + 0) * 64 + r] = v.x;
            A[(k4 * 4 + 1) * 64 + r] = v.y;
            A[(k4 * 4 + 2) * 64 + r] = v.z;
            A[(k4 * 4 + 3) * 64 + r] = v.w;
        }
        // stage W1 chunk [64][128] -> B
#pragma unroll
        for (int i = 0; i < 8; ++i) {
            const int lin = (i * 256 + t) * 4;
            *(float4*)(B + lin) = *(const float4*)(W1 + (size_t)c * 64 * H + lin);
        }
        __syncthreads();
        for (int kk = 0; kk < 64; ++kk) {
            const float4 xa = *(const float4*)(A + kk * 64 + r0);
            const float4 xb = *(const float4*)(A + kk * 64 + r0 + 4);
            const float4 w  = *(const float4*)(B + kk * H + j0);
            const float xs[8] = {xa.x, xa.y, xa.z, xa.w, xb.x, xb.y, xb.z, xb.w};
            const float ws[4] = {w.x, w.y, w.z, w.w};
#pragma unroll
            for (int ee = 0; ee < 8; ++ee)
#pragma unroll
                for (int jj = 0; jj < 4; ++jj)
                    acc[ee][jj] += xs[ee] * ws[jj];
        }
    }
    // relu -> h1T in C[j][r]  (each thread owns distinct (j,r) cells; no sync needed before)
#pragma unroll
    for (int jj = 0; jj < 4; ++jj) {
        float4 lo, hi;
        lo.x = fmaxf(acc[0][jj], 0.f); lo.y = fmaxf(acc[1][jj], 0.f);
        lo.z = fmaxf(acc[2][jj], 0.f); lo.w = fmaxf(acc[3][jj], 0.f);
        hi.x = fmaxf(acc[4][jj], 0.f); hi.y = fmaxf(acc[5][jj], 0.f);
        hi.z = fmaxf(acc[6][jj], 0.f); hi.w = fmaxf(acc[7][jj], 0.f);
        *(float4*)(C + (j0 + jj) * 64 + r0)     = lo;
        *(float4*)(C + (j0 + jj) * 64 + r0 + 4) = hi;
    }

    // ---- layer 2: K=128 from C, W2 chunks [32][128] in A, out h2T -> B ----
    float acc2[8][4];
    {
        const float4 bb = *(const float4*)(b2 + j0);
#pragma unroll
        for (int ee = 0; ee < 8; ++ee) {
            acc2[ee][0] = bb.x; acc2[ee][1] = bb.y; acc2[ee][2] = bb.z; acc2[ee][3] = bb.w;
        }
    }
    for (int c = 0; c < 4; ++c) {
        __syncthreads();  // C writes visible (c==0); prior A readers done
#pragma unroll
        for (int i = 0; i < 4; ++i) {
            const int lin = (i * 256 + t) * 4;
            *(float4*)(A + lin) = *(const float4*)(W2 + (size_t)c * 32 * H + lin);
        }
        __syncthreads();
        for (int kk = 0; kk < 32; ++kk) {
            const int k = c * 32 + kk;
            const float4 xa = *(const float4*)(C + k * 64 + r0);
            const float4 xb = *(const float4*)(C + k * 64 + r0 + 4);
            const float4 w  = *(const float4*)(A + kk * H + j0);
            const float xs[8] = {xa.x, xa.y, xa.z, xa.w, xb.x, xb.y, xb.z, xb.w};
            const float ws[4] = {w.x, w.y, w.z, w.w};
#pragma unroll
            for (int ee = 0; ee < 8; ++ee)
#pragma unroll
                for (int jj = 0; jj < 4; ++jj)
                    acc2[ee][jj] += xs[ee] * ws[jj];
        }
    }
    // relu -> h2T in B[j][r] (B's W1 data dead; last B readers finished in layer 1)
#pragma unroll
    for (int jj = 0; jj < 4; ++jj) {
        float4 lo, hi;
        lo.x = fmaxf(acc2[0][jj], 0.f); lo.y = fmaxf(acc2[1][jj], 0.f);
        lo.z = fmaxf(acc2[2][jj], 0.f); lo.w = fmaxf(acc2[3][jj], 0.f);
        hi.x = fmaxf(acc2[4][jj], 0.f); hi.y = fmaxf(acc2[5][jj], 0.f);
        hi.z = fmaxf(acc2[6][jj], 0.f); hi.w = fmaxf(acc2[7][jj], 0.f);
        *(float4*)(B + (j0 + jj) * 64 + r0)     = lo;
        *(float4*)(B + (j0 + jj) * 64 + r0 + 4) = hi;
    }

    // ---- layer 3: K=128 from B, W3 chunks [64][64] in A, 8 rows x 2 cols ----
    const int jb = jg * 2;
    float accO[8][2];
    {
        const float2 bb = *(const float2*)(b3 + jb);
#pragma unroll
        for (int ee = 0; ee < 8; ++ee) { accO[ee][0] = bb.x; accO[ee][1] = bb.y; }
    }
    for (int c = 0; c < 2; ++c) {
        __syncthreads();  // h2T writes visible (c==0); prior A readers done
#pragma unroll
        for (int i = 0; i < 4; ++i) {
            const int lin = (i * 256 + t) * 4;
            *(float4*)(A + lin) = *(const float4*)(W3 + (size_t)c * 64 * 64 + lin);
        }
        __syncthreads();
        for (int kk = 0; kk < 64; ++kk) {
            const int k = c * 64 + kk;
            const float4 xa = *(const float4*)(B + k * 64 + r0);
            const float4 xb = *(const float4*)(B + k * 64 + r0 + 4);
            const float2 w  = *(const float2*)(A + kk * 64 + jb);
            const float xs[8] = {xa.x, xa.y, xa.z, xa.w, xb.x, xb.y, xb.z, xb.w};
#pragma unroll
            for (int ee = 0; ee < 8; ++ee) {
                accO[ee][0] += xs[ee] * w.x;
                accO[ee][1] += xs[ee] * w.y;
            }
        }
    }

    // ---- epilogue: store + (EDGE) scatter-add msgs ----
#pragma unroll
    for (int ee = 0; ee < 8; ++ee) {
        const int row = base + r0 + ee;
        if (row < M) {
            float2 v; v.x = accO[ee][0]; v.y = accO[ee][1];
            *(float2*)(out + (size_t)row * 64 + jb) = v;
            if (IS_EDGE) {
                const int d = dst[row];
                atomicAdd(msgs_out + (size_t)d * 64 + jb,     v.x);
                atomicAdd(msgs_out + (size_t)d * 64 + jb + 1, v.y);
            }
        }
    }
}

// ---------------------------------------------------------------------------
// Per-graph segment sum: LDS 16x64 accumulator per block, then global atomics.
// ---------------------------------------------------------------------------
__global__ __launch_bounds__(256)
void seg_comb_kernel(const float* __restrict__ vals, const int* __restrict__ seg,
                     float* comb, int M, int RPB)
{
    __shared__ float acc[1024];  // 16 graphs x 64
    const int t = threadIdx.x;
#pragma unroll
    for (int i = 0; i < 4; ++i) acc[i * 256 + t] = 0.f;
    __syncthreads();
    const int j  = t & 63;
    const int rr = t >> 6;  // 0..3
    const int row0 = blockIdx.x * RPB;
    int rend = row0 + RPB; if (rend > M) rend = M;
    for (int r = row0 + rr; r < rend; r += 4) {
        const int g = seg[r];
        atomicAdd(acc + g * 64 + j, vals[(size_t)r * 64 + j]);
    }
    __syncthreads();
#pragma unroll
    for (int i = 0; i < 4; ++i) {
        const int slot = i * 256 + t;
        atomicAdd(comb + slot, acc[slot]);
    }
}

// ---------------------------------------------------------------------------
// Global-state MLP over 16 graphs: inp_u = [n_comb | e_comb | g_repr] (192)
// ---------------------------------------------------------------------------
__global__ __launch_bounds__(256)
void u_kernel(const float* __restrict__ ncomb, const float* __restrict__ ecomb,
              const float* __restrict__ gr,
              const float* __restrict__ W1, const float* __restrict__ b1,
              const float* __restrict__ W2, const float* __restrict__ b2,
              const float* __restrict__ W3, const float* __restrict__ b3,
              float* uout)
{
    __shared__ float X[16 * 192];
    __shared__ float Hs[16 * 128];
    __shared__ float H2s[16 * 128];
    const int t = threadIdx.x;
#pragma unroll
    for (int i = 0; i < 12; ++i) {
        const int idx = i * 256 + t;       // 0..3071
        const int g = idx / 192, col = idx % 192;
        float v;
        if      (col < 64)  v = ncomb[g * 64 + col];
        else if (col < 128) v = ecomb[g * 64 + col - 64];
        else                v = gr[g * 64 + col - 128];
        X[idx] = v;
    }
    __syncthreads();
    {
        const int j = t & 127, gb = t >> 7;
        float a[8];
#pragma unroll
        for (int gi = 0; gi < 8; ++gi) a[gi] = b1[j];
        for (int k = 0; k < 192; ++k) {
            const float w = W1[k * 128 + j];
#pragma unroll
            for (int gi = 0; gi < 8; ++gi) a[gi] += X[(gb + gi * 2) * 192 + k] * w;
        }
#pragma unroll
        for (int gi = 0; gi < 8; ++gi) Hs[(gb + gi * 2) * 128 + j] = fmaxf(a[gi], 0.f);
    }
    __syncthreads();
    {
        const int j = t & 127, gb = t >> 7;
        float a[8];
#pragma unroll
        for (int gi = 0; gi < 8; ++gi) a[gi] = b2[j];
        for (int k = 0; k < 128; ++k) {
            const float w = W2[k * 128 + j];
#pragma unroll
            for (int gi = 0; gi < 8; ++gi) a[gi] += Hs[(gb + gi * 2) * 128 + k] * w;
        }
#pragma unroll
        for (int gi = 0; gi < 8; ++gi) H2s[(gb + gi * 2) * 128 + j] = fmaxf(a[gi], 0.f);
    }
    __syncthreads();
    {
        const int j = t & 63, gb = t >> 6;
        float a[4];
#pragma unroll
        for (int gi = 0; gi < 4; ++gi) a[gi] = b3[j];
        for (int k = 0; k < 128; ++k) {
            const float w = W3[k * 64 + j];
#pragma unroll
            for (int gi = 0; gi < 4; ++gi) a[gi] += H2s[(gb + gi * 4) * 128 + k] * w;
        }
#pragma unroll
        for (int gi = 0; gi < 4; ++gi) uout[(gb + gi * 4) * 64 + j] = a[gi];
    }
}

// ---------------------------------------------------------------------------
extern "C" void kernel_launch(void* const* d_in, const int* in_sizes, int n_in,
                              void* d_out, int out_size, void* d_ws, size_t ws_size,
                              hipStream_t stream)
{
    const float* edge_feat = (const float*)d_in[0];
    const float* node_feat = (const float*)d_in[1];
    const float* g_repr    = (const float*)d_in[2];
    const int*   src       = (const int*)d_in[3];
    const int*   dst       = (const int*)d_in[4];
    const int*   e2g       = (const int*)d_in[5];
    const int*   n2g       = (const int*)d_in[6];
    const float* We1 = (const float*)d_in[7];  const float* be1 = (const float*)d_in[8];
    const float* We2 = (const float*)d_in[9];  const float* be2 = (const float*)d_in[10];
    const float* We3 = (const float*)d_in[11]; const float* be3 = (const float*)d_in[12];
    const float* Wn1 = (const float*)d_in[13]; const float* bn1 = (const float*)d_in[14];
    const float* Wn2 = (const float*)d_in[15]; const float* bn2 = (const float*)d_in[16];
    const float* Wn3 = (const float*)d_in[17]; const float* bn3 = (const float*)d_in[18];
    const float* Wu1 = (const float*)d_in[19]; const float* bu1 = (const float*)d_in[20];
    const float* Wu2 = (const float*)d_in[21]; const float* bu2 = (const float*)d_in[22];
    const float* Wu3 = (const float*)d_in[23]; const float* bu3 = (const float*)d_in[24];

    const int E = in_sizes[3];   // 400000
    const int N = in_sizes[6];   // 50000

    float* e_out = (float*)d_out;
    float* n_out = e_out + (size_t)E * 64;   // doubles as msgs scratch (overwritten in place)
    float* u_out = n_out + (size_t)N * 64;
    float* ecomb = (float*)d_ws;             // 1024 floats
    float* ncomb = ecomb + 1024;             // 1024 floats

    // zero msgs accumulator (n_out region) and per-graph accumulators
    hipMemsetAsync(n_out, 0, (size_t)N * 64 * sizeof(float), stream);
    hipMemsetAsync(d_ws, 0, 2048 * sizeof(float), stream);

    // 1) edge MLP + scatter msgs
    mlp_tile_kernel<4, true><<<(E + TE - 1) / TE, 256, 0, stream>>>(
        edge_feat, node_feat, g_repr, src, dst, e2g,
        We1, be1, We2, be2, We3, be3, e_out, n_out, E);
    // 2) e_comb = per-graph sum of e_out
    seg_comb_kernel<<<(E + 255) / 256, 256, 0, stream>>>(e_out, e2g, ecomb, E, 256);
    // 3) node MLP (reads msgs from n_out region, overwrites it with n_out)
    mlp_tile_kernel<3, false><<<(N + TE - 1) / TE, 256, 0, stream>>>(
        node_feat, n_out, g_repr, nullptr, nullptr, n2g,
        Wn1, bn1, Wn2, bn2, Wn3, bn3, n_out, nullptr, N);
    // 4) n_comb = per-graph sum of n_out
    seg_comb_kernel<<<(N + 255) / 256, 256, 0, stream>>>(n_out, n2g, ncomb, N, 256);
    // 5) global MLP
    u_kernel<<<1, 256, 0, stream>>>(ncomb, ecomb, g_repr,
                                    Wu1, bu1, Wu2, bu2, Wu3, bu3, u_out);
}

// Round 2
// 404.767 us; speedup vs baseline: 2.5907x; 2.5907x over previous
//
#include <hip/hip_runtime.h>
#include <cstdint>

// GraphNets block, bf16-MFMA version.
// DE=DN=DU=DO=64, H1=H2=128. K_edge=256, K_node=192.
// mfma_f32_16x16x32_bf16: A lane l: row=l&15, k=(l>>4)*8+j ; B: col=l&15, k=(l>>4)*8+j
// C/D: col=lane&15, row=(lane>>4)*4+reg   [guide §3, m89-verified]

typedef short short8 __attribute__((ext_vector_type(8)));
typedef float f32x4 __attribute__((ext_vector_type(4)));

#define MFMA16(a, b, c) __builtin_amdgcn_mfma_f32_16x16x32_bf16(a, b, c, 0, 0, 0)

__device__ __forceinline__ short f2bf(float x) {
    union { __bf16 b; short s; } u; u.b = (__bf16)x; return u.s;
}

// XOR swizzle on 16B slots within a row: breaks the power-of-2 row-stride
// bank conflict for ds_read_b128 A-fragments (guide §6 G4).
__device__ __forceinline__ int swz(int row, int byteInRow, int rowStrideBytes) {
    int slot = byteInRow >> 4;
    int rem  = byteInRow & 15;
    slot ^= (row & 7);
    return row * rowStrideBytes + slot * 16 + rem;
}

// ---------------------------------------------------------------------------
// Weight prep: fp32 [K][N] -> bf16 pre-swizzled B-fragments (frag = kf*NF+nf,
// 1024B each, lane-contiguous). 208 frags total.
// Region offsets (bytes): We1f 0 (64KB) | We2f 65536 | We3f 98304 | Wn1f 114688
//                         | Wn2f 163840 | Wn3f 196608 | end 212992
// ---------------------------------------------------------------------------
__global__ __launch_bounds__(256)
void prep_weights(const float* __restrict__ We1, const float* __restrict__ We2,
                  const float* __restrict__ We3, const float* __restrict__ Wn1,
                  const float* __restrict__ Wn2, const float* __restrict__ Wn3,
                  char* __restrict__ out)
{
    const int fg = blockIdx.x * 4 + (threadIdx.x >> 6);
    if (fg >= 208) return;
    const int lane = threadIdx.x & 63;
    const float* W; int Ncols, f; size_t obase;
    if      (fg < 64)  { W = We1; Ncols = 128; f = fg;       obase = 0;      }
    else if (fg < 96)  { W = We2; Ncols = 128; f = fg - 64;  obase = 65536;  }
    else if (fg < 112) { W = We3; Ncols = 64;  f = fg - 96;  obase = 98304;  }
    else if (fg < 160) { W = Wn1; Ncols = 128; f = fg - 112; obase = 114688; }
    else if (fg < 192) { W = Wn2; Ncols = 128; f = fg - 160; obase = 163840; }
    else               { W = Wn3; Ncols = 64;  f = fg - 192; obase = 196608; }
    const int NF = Ncols >> 4;
    const int kf = f / NF, nf = f - kf * NF;
    const int k0 = kf * 32 + (lane >> 4) * 8;
    const int col = nf * 16 + (lane & 15);
    union { short s[8]; uint4 u; } pk;
#pragma unroll
    for (int j = 0; j < 8; ++j) pk.s[j] = f2bf(W[(size_t)(k0 + j) * Ncols + col]);
    *(uint4*)(out + obase + ((size_t)f * 64 + lane) * 16) = pk.u;
}

// ---------------------------------------------------------------------------
// MFMA 3-layer MLP. Block = 256 thr (4 waves), tile = 128 rows.
// Wave w: rows [w*32, w*32+32). acc[rf][nf] = f32x4 per 16x16 frag.
// LDS: X 16KB (gather chunk, bf16 swizzled) | h1 32KB | h2 32KB = 80KB.
// comb (16 graphs x 64, f32) aliases X after layer 1.
// Epilogue: store out, (EDGE) atomic msgs scatter, per-graph comb -> replica.
// ---------------------------------------------------------------------------
template <int NCHUNK, bool IS_EDGE>
__global__ __launch_bounds__(256, 2)
void mlp_mfma_kernel(const float* __restrict__ feat0,
                     const float* feat1,             // node_feat / msgs (aliases out)
                     const float* __restrict__ gr,
                     const int* __restrict__ srcIdx, const int* __restrict__ dstIdx,
                     const int* __restrict__ seg,
                     const char* __restrict__ W1f, const float* __restrict__ b1,
                     const char* __restrict__ W2f, const float* __restrict__ b2,
                     const char* __restrict__ W3f, const float* __restrict__ b3,
                     float* out, float* msgs_out, float* comb_rep, int M)
{
    __shared__ char lds[81920];
    char* Xs  = lds;            // 16 KB
    char* H1s = lds + 16384;    // 32 KB
    char* H2s = lds + 49152;    // 32 KB
    float* combs = (float*)lds; // 4 KB, aliases Xs (dead after layer 1)

    const int t    = threadIdx.x;
    const int lane = t & 63;
    const int w    = t >> 6;
    const int l15  = lane & 15;
    const int l4   = lane >> 4;          // 0..3
    const int base = blockIdx.x * 128;
    const int wrow = w * 32;

    // ---- layer 1 ----
    f32x4 acc[2][8];
#pragma unroll
    for (int nf = 0; nf < 8; ++nf) {
        const float bv = b1[nf * 16 + l15];
        acc[0][nf] = f32x4{bv, bv, bv, bv};
        acc[1][nf] = f32x4{bv, bv, bv, bv};
    }

    for (int c = 0; c < NCHUNK; ++c) {
        __syncthreads();
        // gather 128 rows x 64 cols fp32 -> bf16 swizzled LDS
#pragma unroll
        for (int i = 0; i < 8; ++i) {
            const int slot = i * 256 + t;      // 0..2047
            const int r  = slot >> 4;          // 0..127
            const int k4 = slot & 15;          // float4 index
            const int row = base + r;
            float4 v = make_float4(0.f, 0.f, 0.f, 0.f);
            if (row < M) {
                const float* p;
                if (IS_EDGE) {
                    p = (c == 0) ? feat0 + (size_t)row * 64
                      : (c == 1) ? feat1 + (size_t)srcIdx[row] * 64
                      : (c == 2) ? feat1 + (size_t)dstIdx[row] * 64
                      :            gr    + (size_t)seg[row] * 64;
                } else {
                    p = (c == 0) ? feat0 + (size_t)row * 64
                      : (c == 1) ? feat1 + (size_t)row * 64
                      :            gr    + (size_t)seg[row] * 64;
                }
                v = *(const float4*)(p + k4 * 4);
            }
            union { uint2 u; short s[4]; } pk;
            pk.s[0] = f2bf(v.x); pk.s[1] = f2bf(v.y);
            pk.s[2] = f2bf(v.z); pk.s[3] = f2bf(v.w);
            *(uint2*)(Xs + swz(r, k4 * 8, 128)) = pk.u;
        }
        __syncthreads();
#pragma unroll
        for (int kf2 = 0; kf2 < 2; ++kf2) {
            const int kf = c * 2 + kf2;
            const int kb = (kf2 * 32 + l4 * 8) * 2;   // byte-in-row of k0
            short8 a0 = *(short8*)(Xs + swz(wrow + l15,      kb, 128));
            short8 a1 = *(short8*)(Xs + swz(wrow + 16 + l15, kb, 128));
#pragma unroll
            for (int nf = 0; nf < 8; ++nf) {
                short8 bw = *(const short8*)(W1f + ((size_t)(kf * 8 + nf) * 64 + lane) * 16);
                acc[0][nf] = MFMA16(a0, bw, acc[0][nf]);
                acc[1][nf] = MFMA16(a1, bw, acc[1][nf]);
            }
        }
    }
    // relu -> h1 (bf16, swizzled). Own cells; sync after so all waves visible.
#pragma unroll
    for (int rf = 0; rf < 2; ++rf)
#pragma unroll
        for (int nf = 0; nf < 8; ++nf)
#pragma unroll
            for (int q = 0; q < 4; ++q) {
                const int row = wrow + rf * 16 + l4 * 4 + q;
                const int col = nf * 16 + l15;
                *(short*)(H1s + swz(row, col * 2, 256)) =
                    f2bf(fmaxf(acc[rf][nf][q], 0.f));
            }
    __syncthreads();

    // ---- layer 2: K=128 ----
    f32x4 acc2[2][8];
#pragma unroll
    for (int nf = 0; nf < 8; ++nf) {
        const float bv = b2[nf * 16 + l15];
        acc2[0][nf] = f32x4{bv, bv, bv, bv};
        acc2[1][nf] = f32x4{bv, bv, bv, bv};
    }
#pragma unroll
    for (int kf = 0; kf < 4; ++kf) {
        const int kb = (kf * 32 + l4 * 8) * 2;
        short8 a0 = *(short8*)(H1s + swz(wrow + l15,      kb, 256));
        short8 a1 = *(short8*)(H1s + swz(wrow + 16 + l15, kb, 256));
#pragma unroll
        for (int nf = 0; nf < 8; ++nf) {
            short8 bw = *(const short8*)(W2f + ((size_t)(kf * 8 + nf) * 64 + lane) * 16);
            acc2[0][nf] = MFMA16(a0, bw, acc2[0][nf]);
            acc2[1][nf] = MFMA16(a1, bw, acc2[1][nf]);
        }
    }
#pragma unroll
    for (int rf = 0; rf < 2; ++rf)
#pragma unroll
        for (int nf = 0; nf < 8; ++nf)
#pragma unroll
            for (int q = 0; q < 4; ++q) {
                const int row = wrow + rf * 16 + l4 * 4 + q;
                const int col = nf * 16 + l15;
                *(short*)(H2s + swz(row, col * 2, 256)) =
                    f2bf(fmaxf(acc2[rf][nf][q], 0.f));
            }
    __syncthreads();

    // ---- layer 3: K=128, N=64 ----
    f32x4 acc3[2][4];
#pragma unroll
    for (int nf = 0; nf < 4; ++nf) {
        const float bv = b3[nf * 16 + l15];
        acc3[0][nf] = f32x4{bv, bv, bv, bv};
        acc3[1][nf] = f32x4{bv, bv, bv, bv};
    }
#pragma unroll
    for (int kf = 0; kf < 4; ++kf) {
        const int kb = (kf * 32 + l4 * 8) * 2;
        short8 a0 = *(short8*)(H2s + swz(wrow + l15,      kb, 256));
        short8 a1 = *(short8*)(H2s + swz(wrow + 16 + l15, kb, 256));
#pragma unroll
        for (int nf = 0; nf < 4; ++nf) {
            short8 bw = *(const short8*)(W3f + ((size_t)(kf * 4 + nf) * 64 + lane) * 16);
            acc3[0][nf] = MFMA16(a0, bw, acc3[0][nf]);
            acc3[1][nf] = MFMA16(a1, bw, acc3[1][nf]);
        }
    }

    // ---- epilogue ----
    __syncthreads();                       // everyone past Xs use -> reuse as comb
#pragma unroll
    for (int i = 0; i < 4; ++i) combs[i * 256 + t] = 0.f;
    __syncthreads();

#pragma unroll
    for (int rf = 0; rf < 2; ++rf)
#pragma unroll
        for (int q = 0; q < 4; ++q) {
            const int row = base + wrow + rf * 16 + l4 * 4 + q;
            if (row < M) {
                const int g = seg[row];
                int d = 0;
                if (IS_EDGE) d = dstIdx[row];
#pragma unroll
                for (int nf = 0; nf < 4; ++nf) {
                    const int col = nf * 16 + l15;
                    const float v = acc3[rf][nf][q];
                    out[(size_t)row * 64 + col] = v;
                    if (IS_EDGE) atomicAdd(msgs_out + (size_t)d * 64 + col, v);
                    atomicAdd(&combs[g * 64 + col], v);
                }
            }
        }
    __syncthreads();
    float* rep = comb_rep + (size_t)(blockIdx.x & 63) * 1024;
#pragma unroll
    for (int i = 0; i < 4; ++i) {
        const int s = i * 256 + t;
        atomicAdd(rep + s, combs[s]);
    }
}

// ---------------------------------------------------------------------------
// Reduce 64 replicas -> ecomb|ncomb (2048 slots contiguous).
// ---------------------------------------------------------------------------
__global__ __launch_bounds__(256)
void reduce_rep_kernel(const float* __restrict__ rep, float* __restrict__ outv)
{
    const int s = blockIdx.x * 256 + threadIdx.x;   // 0..2047
    const int arr = s >> 10, idx = s & 1023;
    const float* p = rep + (size_t)arr * 65536 + idx;
    float v = 0.f;
#pragma unroll 8
    for (int r = 0; r < 64; ++r) v += p[(size_t)r * 1024];
    outv[s] = v;
}

// ---------------------------------------------------------------------------
// Global-state MLP over 16 graphs (fp32 VALU; tiny).
// ---------------------------------------------------------------------------
__global__ __launch_bounds__(256)
void u_kernel(const float* __restrict__ ncomb, const float* __restrict__ ecomb,
              const float* __restrict__ gr,
              const float* __restrict__ W1, const float* __restrict__ b1,
              const float* __restrict__ W2, const float* __restrict__ b2,
              const float* __restrict__ W3, const float* __restrict__ b3,
              float* uout)
{
    __shared__ float X[16 * 192];
    __shared__ float Hs[16 * 128];
    __shared__ float H2s[16 * 128];
    const int t = threadIdx.x;
#pragma unroll
    for (int i = 0; i < 12; ++i) {
        const int idx = i * 256 + t;
        const int g = idx / 192, col = idx % 192;
        float v;
        if      (col < 64)  v = ncomb[g * 64 + col];
        else if (col < 128) v = ecomb[g * 64 + col - 64];
        else                v = gr[g * 64 + col - 128];
        X[idx] = v;
    }
    __syncthreads();
    {
        const int j = t & 127, gb = t >> 7;
        float a[8];
#pragma unroll
        for (int gi = 0; gi < 8; ++gi) a[gi] = b1[j];
        for (int k = 0; k < 192; ++k) {
            const float wv = W1[k * 128 + j];
#pragma unroll
            for (int gi = 0; gi < 8; ++gi) a[gi] += X[(gb + gi * 2) * 192 + k] * wv;
        }
#pragma unroll
        for (int gi = 0; gi < 8; ++gi) Hs[(gb + gi * 2) * 128 + j] = fmaxf(a[gi], 0.f);
    }
    __syncthreads();
    {
        const int j = t & 127, gb = t >> 7;
        float a[8];
#pragma unroll
        for (int gi = 0; gi < 8; ++gi) a[gi] = b2[j];
        for (int k = 0; k < 128; ++k) {
            const float wv = W2[k * 128 + j];
#pragma unroll
            for (int gi = 0; gi < 8; ++gi) a[gi] += Hs[(gb + gi * 2) * 128 + k] * wv;
        }
#pragma unroll
        for (int gi = 0; gi < 8; ++gi) H2s[(gb + gi * 2) * 128 + j] = fmaxf(a[gi], 0.f);
    }
    __syncthreads();
    {
        const int j = t & 63, gb = t >> 6;
        float a[4];
#pragma unroll
        for (int gi = 0; gi < 4; ++gi) a[gi] = b3[j];
        for (int k = 0; k < 128; ++k) {
            const float wv = W3[k * 64 + j];
#pragma unroll
            for (int gi = 0; gi < 4; ++gi) a[gi] += H2s[(gb + gi * 4) * 128 + k] * wv;
        }
#pragma unroll
        for (int gi = 0; gi < 4; ++gi) uout[(gb + gi * 4) * 64 + j] = a[gi];
    }
}

// ---------------------------------------------------------------------------
extern "C" void kernel_launch(void* const* d_in, const int* in_sizes, int n_in,
                              void* d_out, int out_size, void* d_ws, size_t ws_size,
                              hipStream_t stream)
{
    const float* edge_feat = (const float*)d_in[0];
    const float* node_feat = (const float*)d_in[1];
    const float* g_repr    = (const float*)d_in[2];
    const int*   src       = (const int*)d_in[3];
    const int*   dst       = (const int*)d_in[4];
    const int*   e2g       = (const int*)d_in[5];
    const int*   n2g       = (const int*)d_in[6];
    const float* We1 = (const float*)d_in[7];  const float* be1 = (const float*)d_in[8];
    const float* We2 = (const float*)d_in[9];  const float* be2 = (const float*)d_in[10];
    const float* We3 = (const float*)d_in[11]; const float* be3 = (const float*)d_in[12];
    const float* Wn1 = (const float*)d_in[13]; const float* bn1 = (const float*)d_in[14];
    const float* Wn2 = (const float*)d_in[15]; const float* bn2 = (const float*)d_in[16];
    const float* Wn3 = (const float*)d_in[17]; const float* bn3 = (const float*)d_in[18];
    const float* Wu1 = (const float*)d_in[19]; const float* bu1 = (const float*)d_in[20];
    const float* Wu2 = (const float*)d_in[21]; const float* bu2 = (const float*)d_in[22];
    const float* Wu3 = (const float*)d_in[23]; const float* bu3 = (const float*)d_in[24];

    const int E = in_sizes[3];   // 400000
    const int N = in_sizes[6];   // 50000

    float* e_out = (float*)d_out;
    float* n_out = e_out + (size_t)E * 64;   // doubles as msgs (overwritten in place)
    float* u_out = n_out + (size_t)N * 64;

    // ws layout (bytes):
    //   0       ecomb_rep  64x1024 f32 (256KB)
    //   262144  ncomb_rep  64x1024 f32 (256KB)
    //   524288  ecomb 1024 f32 | ncomb 1024 f32 (8KB)
    //   532480  bf16 swizzled weights (212992 B)
    char* wsc = (char*)d_ws;
    float* ecomb_rep = (float*)wsc;
    float* ncomb_rep = (float*)(wsc + 262144);
    float* ecomb     = (float*)(wsc + 524288);
    float* ncomb     = ecomb + 1024;
    char*  wf        = wsc + 532480;
    const char* We1f = wf;          const char* We2f = wf + 65536;
    const char* We3f = wf + 98304;  const char* Wn1f = wf + 114688;
    const char* Wn2f = wf + 163840; const char* Wn3f = wf + 196608;

    // zero msgs accumulator and comb replicas
    hipMemsetAsync(n_out, 0, (size_t)N * 64 * sizeof(float), stream);
    hipMemsetAsync(wsc, 0, 524288, stream);

    prep_weights<<<52, 256, 0, stream>>>(We1, We2, We3, Wn1, Wn2, Wn3, wf);

    // 1) edge MLP + msgs scatter + fused e_comb
    mlp_mfma_kernel<4, true><<<(E + 127) / 128, 256, 0, stream>>>(
        edge_feat, node_feat, g_repr, src, dst, e2g,
        We1f, be1, We2f, be2, We3f, be3, e_out, n_out, ecomb_rep, E);
    // 2) node MLP (reads msgs from n_out region, overwrites in place) + fused n_comb
    mlp_mfma_kernel<3, false><<<(N + 127) / 128, 256, 0, stream>>>(
        node_feat, n_out, g_repr, nullptr, nullptr, n2g,
        Wn1f, bn1, Wn2f, bn2, Wn3f, bn3, n_out, nullptr, ncomb_rep, N);
    // 3) reduce replicas -> ecomb|ncomb
    reduce_rep_kernel<<<8, 256, 0, stream>>>(ecomb_rep, ecomb);
    // 4) global MLP
    u_kernel<<<1, 256, 0, stream>>>(ncomb, ecomb, g_repr,
                                    Wu1, bu1, Wu2, bu2, Wu3, bu3, u_out);
}

// Round 3
// 364.065 us; speedup vs baseline: 2.8803x; 1.1118x over previous
//
#include <hip/hip_runtime.h>
#include <cstdint>

// GraphNets block, bf16-MFMA, wave-private barrier-free MLP.
// mfma_f32_16x16x32_bf16: A lane l: row=l&15, k=(l>>4)*8+j ; B: col=l&15, same k
// C/D: col=lane&15, row=(lane>>4)*4+reg   [guide §3, m89-verified; v2 passed]

typedef short short8 __attribute__((ext_vector_type(8)));
typedef float f32x4 __attribute__((ext_vector_type(4)));

#define MFMA16(a, b, c) __builtin_amdgcn_mfma_f32_16x16x32_bf16(a, b, c, 0, 0, 0)

__device__ __forceinline__ short f2bf(float x) {
    union { __bf16 b; short s; } u; u.b = (__bf16)x; return u.s;
}

// ---------------------------------------------------------------------------
// Weight prep: fp32 [K][N] -> bf16 pre-swizzled B-fragments (frag kf*NF+nf,
// 1024B each, lane-contiguous).  (unchanged from v2 — verified by v2 pass)
// ---------------------------------------------------------------------------
__global__ __launch_bounds__(256)
void prep_weights(const float* __restrict__ We1, const float* __restrict__ We2,
                  const float* __restrict__ We3, const float* __restrict__ Wn1,
                  const float* __restrict__ Wn2, const float* __restrict__ Wn3,
                  char* __restrict__ out)
{
    const int fg = blockIdx.x * 4 + (threadIdx.x >> 6);
    if (fg >= 208) return;
    const int lane = threadIdx.x & 63;
    const float* W; int Ncols, f; size_t obase;
    if      (fg < 64)  { W = We1; Ncols = 128; f = fg;       obase = 0;      }
    else if (fg < 96)  { W = We2; Ncols = 128; f = fg - 64;  obase = 65536;  }
    else if (fg < 112) { W = We3; Ncols = 64;  f = fg - 96;  obase = 98304;  }
    else if (fg < 160) { W = Wn1; Ncols = 128; f = fg - 112; obase = 114688; }
    else if (fg < 192) { W = Wn2; Ncols = 128; f = fg - 160; obase = 163840; }
    else               { W = Wn3; Ncols = 64;  f = fg - 192; obase = 196608; }
    const int NF = Ncols >> 4;
    const int kf = f / NF, nf = f - kf * NF;
    const int k0 = kf * 32 + (lane >> 4) * 8;
    const int col = nf * 16 + (lane & 15);
    union { short s[8]; uint4 u; } pk;
#pragma unroll
    for (int j = 0; j < 8; ++j) pk.s[j] = f2bf(W[(size_t)(k0 + j) * Ncols + col]);
    *(uint4*)(out + obase + ((size_t)f * 64 + lane) * 16) = pk.u;
}

// ---------------------------------------------------------------------------
// Wave-private 3-layer MLP. Block = 256 thr = 4 waves; wave owns 16 rows.
// Per-wave 8KB LDS slice: X [16][512B swz] ; h1 (4KB, stride 256B) aliases
// X[0:4K] after layer-1; h2 at +4096 aliases X[4K:8K] after layer-2.
// No __syncthreads between staging and epilogue (per-wave DS ordering).
// comb: block-shared 4KB LDS (16 graphs x 64), 2 barriers total.
// ---------------------------------------------------------------------------
template <int NQ, bool IS_EDGE>
__global__ __launch_bounds__(256, 4)
void mlp_wave_kernel(const float* __restrict__ feat0,
                     const float* feat1,             // node_feat / msgs (aliases out)
                     const float* __restrict__ gr,
                     const int* __restrict__ srcIdx, const int* __restrict__ dstIdx,
                     const int* __restrict__ seg,
                     const char* __restrict__ W1f, const float* __restrict__ b1,
                     const char* __restrict__ W2f, const float* __restrict__ b2,
                     const char* __restrict__ W3f, const float* __restrict__ b3,
                     float* out, float* msgs_out, float* comb_rep, int M)
{
    __shared__ char lds[36864];              // 4x8KB wave slices + 4KB comb
    float* combs = (float*)(lds + 32768);

    const int t    = threadIdx.x;
    const int lane = t & 63;
    const int w    = t >> 6;
    const int l15  = lane & 15;
    const int l4   = lane >> 4;
    char* Ws = lds + w * 8192;
    const int base = blockIdx.x * 64 + w * 16;   // wave's first global row

#pragma unroll
    for (int i = 0; i < 4; ++i) combs[i * 256 + t] = 0.f;
    __syncthreads();   // comb ready (before any loads are issued)

    // ---- stage X: 16 rows x NQ*64 f32 -> bf16 swizzled, two 8-row batches ----
    // lane role: source quarter = l4, float4-in-source = l15.
    for (int half = 0; half < 2; ++half) {
        int idx8[8];
#pragma unroll
        for (int i = 0; i < 8; ++i) {
            const int row = base + half * 8 + i;
            int idx = -1;
            if (row < M) {
                if (IS_EDGE) {
                    idx = (l4 == 0) ? row : (l4 == 1) ? srcIdx[row]
                        : (l4 == 2) ? dstIdx[row] : seg[row];
                } else {
                    idx = (l4 == 0) ? row : (l4 == 1) ? row
                        : (l4 == 2) ? seg[row] : -1;
                }
            }
            idx8[i] = idx;
        }
        float4 v8[8];
#pragma unroll
        for (int i = 0; i < 8; ++i) {
            float4 v = make_float4(0.f, 0.f, 0.f, 0.f);
            if (idx8[i] >= 0) {
                const float* p;
                if (IS_EDGE) {
                    p = (l4 == 0) ? feat0 + (size_t)idx8[i] * 64
                      : (l4 == 3) ? gr    + (size_t)idx8[i] * 64
                      :             feat1 + (size_t)idx8[i] * 64;
                } else {
                    p = (l4 == 0) ? feat0 + (size_t)idx8[i] * 64
                      : (l4 == 1) ? feat1 + (size_t)idx8[i] * 64
                      :             gr    + (size_t)idx8[i] * 64;
                }
                v = *(const float4*)(p + l15 * 4);
            }
            v8[i] = v;
        }
#pragma unroll
        for (int i = 0; i < 8; ++i) {
            const int row = half * 8 + i;
            union { uint2 u; short s[4]; } pk;
            pk.s[0] = f2bf(v8[i].x); pk.s[1] = f2bf(v8[i].y);
            pk.s[2] = f2bf(v8[i].z); pk.s[3] = f2bf(v8[i].w);
            const int slot = (l4 * 8 + (l15 >> 1)) ^ (row & 7);
            *(uint2*)(Ws + row * 512 + slot * 16 + (l15 & 1) * 8) = pk.u;
        }
    }

    // ---- layer 1: K = NQ*64 ----
    constexpr int KF1 = NQ * 2;
    f32x4 acc[8];
#pragma unroll
    for (int nf = 0; nf < 8; ++nf) {
        const float bv = b1[nf * 16 + l15];
        acc[nf] = f32x4{bv, bv, bv, bv};
    }
#pragma unroll
    for (int kf = 0; kf < KF1; ++kf) {
        const int slot = (kf * 4 + l4) ^ (l15 & 7);
        short8 a = *(short8*)(Ws + l15 * 512 + slot * 16);
#pragma unroll
        for (int nf = 0; nf < 8; ++nf) {
            short8 bw = *(const short8*)(W1f + ((size_t)(kf * 8 + nf) * 64 + lane) * 16);
            acc[nf] = MFMA16(a, bw, acc[nf]);
        }
    }
    // relu -> h1 (wave-private, aliases X[0:4K]; all X reads already issued)
#pragma unroll
    for (int nf = 0; nf < 8; ++nf)
#pragma unroll
        for (int q = 0; q < 4; ++q) {
            const int row = l4 * 4 + q;
            const int slot = (nf * 2 + (l15 >> 3)) ^ (row & 7);
            *(short*)(Ws + row * 256 + slot * 16 + (l15 & 7) * 2) =
                f2bf(fmaxf(acc[nf][q], 0.f));
        }

    // ---- layer 2: K=128 from h1 ----
    f32x4 acc2[8];
#pragma unroll
    for (int nf = 0; nf < 8; ++nf) {
        const float bv = b2[nf * 16 + l15];
        acc2[nf] = f32x4{bv, bv, bv, bv};
    }
#pragma unroll
    for (int kf = 0; kf < 4; ++kf) {
        const int slot = (kf * 4 + l4) ^ (l15 & 7);
        short8 a = *(short8*)(Ws + l15 * 256 + slot * 16);
#pragma unroll
        for (int nf = 0; nf < 8; ++nf) {
            short8 bw = *(const short8*)(W2f + ((size_t)(kf * 8 + nf) * 64 + lane) * 16);
            acc2[nf] = MFMA16(a, bw, acc2[nf]);
        }
    }
    // relu -> h2 at Ws+4096 (aliases X[4K:8K], long dead)
#pragma unroll
    for (int nf = 0; nf < 8; ++nf)
#pragma unroll
        for (int q = 0; q < 4; ++q) {
            const int row = l4 * 4 + q;
            const int slot = (nf * 2 + (l15 >> 3)) ^ (row & 7);
            *(short*)(Ws + 4096 + row * 256 + slot * 16 + (l15 & 7) * 2) =
                f2bf(fmaxf(acc2[nf][q], 0.f));
        }

    // ---- layer 3: K=128 from h2, N=64 ----
    f32x4 acc3[4];
#pragma unroll
    for (int nf = 0; nf < 4; ++nf) {
        const float bv = b3[nf * 16 + l15];
        acc3[nf] = f32x4{bv, bv, bv, bv};
    }
#pragma unroll
    for (int kf = 0; kf < 4; ++kf) {
        const int slot = (kf * 4 + l4) ^ (l15 & 7);
        short8 a = *(short8*)(Ws + 4096 + l15 * 256 + slot * 16);
#pragma unroll
        for (int nf = 0; nf < 4; ++nf) {
            short8 bw = *(const short8*)(W3f + ((size_t)(kf * 4 + nf) * 64 + lane) * 16);
            acc3[nf] = MFMA16(a, bw, acc3[nf]);
        }
    }

    // ---- epilogue: store out, msgs atomics (EDGE), LDS comb ----
#pragma unroll
    for (int q = 0; q < 4; ++q) {
        const int grow = base + l4 * 4 + q;
        if (grow < M) {
            const int g = seg[grow];
            int d = 0;
            if (IS_EDGE) d = dstIdx[grow];
#pragma unroll
            for (int nf = 0; nf < 4; ++nf) {
                const int col = nf * 16 + l15;
                const float v = acc3[nf][q];
                out[(size_t)grow * 64 + col] = v;
                if (IS_EDGE) atomicAdd(msgs_out + (size_t)d * 64 + col, v);
                atomicAdd(&combs[g * 64 + col], v);
            }
        }
    }
    __syncthreads();
    float* rep = comb_rep + (size_t)(blockIdx.x & 63) * 1024;
#pragma unroll
    for (int i = 0; i < 4; ++i) {
        const int s = i * 256 + t;
        atomicAdd(rep + s, combs[s]);
    }
}

// ---------------------------------------------------------------------------
__global__ __launch_bounds__(256)
void reduce_rep_kernel(const float* __restrict__ rep, float* __restrict__ outv)
{
    const int s = blockIdx.x * 256 + threadIdx.x;   // 0..2047
    const int arr = s >> 10, idx = s & 1023;
    const float* p = rep + (size_t)arr * 65536 + idx;
    float v = 0.f;
#pragma unroll 8
    for (int r = 0; r < 64; ++r) v += p[(size_t)r * 1024];
    outv[s] = v;
}

// ---------------------------------------------------------------------------
__global__ __launch_bounds__(256)
void u_kernel(const float* __restrict__ ncomb, const float* __restrict__ ecomb,
              const float* __restrict__ gr,
              const float* __restrict__ W1, const float* __restrict__ b1,
              const float* __restrict__ W2, const float* __restrict__ b2,
              const float* __restrict__ W3, const float* __restrict__ b3,
              float* uout)
{
    __shared__ float X[16 * 192];
    __shared__ float Hs[16 * 128];
    __shared__ float H2s[16 * 128];
    const int t = threadIdx.x;
#pragma unroll
    for (int i = 0; i < 12; ++i) {
        const int idx = i * 256 + t;
        const int g = idx / 192, col = idx % 192;
        float v;
        if      (col < 64)  v = ncomb[g * 64 + col];
        else if (col < 128) v = ecomb[g * 64 + col - 64];
        else                v = gr[g * 64 + col - 128];
        X[idx] = v;
    }
    __syncthreads();
    {
        const int j = t & 127, gb = t >> 7;
        float a[8];
#pragma unroll
        for (int gi = 0; gi < 8; ++gi) a[gi] = b1[j];
        for (int k = 0; k < 192; ++k) {
            const float wv = W1[k * 128 + j];
#pragma unroll
            for (int gi = 0; gi < 8; ++gi) a[gi] += X[(gb + gi * 2) * 192 + k] * wv;
        }
#pragma unroll
        for (int gi = 0; gi < 8; ++gi) Hs[(gb + gi * 2) * 128 + j] = fmaxf(a[gi], 0.f);
    }
    __syncthreads();
    {
        const int j = t & 127, gb = t >> 7;
        float a[8];
#pragma unroll
        for (int gi = 0; gi < 8; ++gi) a[gi] = b2[j];
        for (int k = 0; k < 128; ++k) {
            const float wv = W2[k * 128 + j];
#pragma unroll
            for (int gi = 0; gi < 8; ++gi) a[gi] += Hs[(gb + gi * 2) * 128 + k] * wv;
        }
#pragma unroll
        for (int gi = 0; gi < 8; ++gi) H2s[(gb + gi * 2) * 128 + j] = fmaxf(a[gi], 0.f);
    }
    __syncthreads();
    {
        const int j = t & 63, gb = t >> 6;
        float a[4];
#pragma unroll
        for (int gi = 0; gi < 4; ++gi) a[gi] = b3[j];
        for (int k = 0; k < 128; ++k) {
            const float wv = W3[k * 64 + j];
#pragma unroll
            for (int gi = 0; gi < 4; ++gi) a[gi] += H2s[(gb + gi * 4) * 128 + k] * wv;
        }
#pragma unroll
        for (int gi = 0; gi < 4; ++gi) uout[(gb + gi * 4) * 64 + j] = a[gi];
    }
}

// ---------------------------------------------------------------------------
extern "C" void kernel_launch(void* const* d_in, const int* in_sizes, int n_in,
                              void* d_out, int out_size, void* d_ws, size_t ws_size,
                              hipStream_t stream)
{
    const float* edge_feat = (const float*)d_in[0];
    const float* node_feat = (const float*)d_in[1];
    const float* g_repr    = (const float*)d_in[2];
    const int*   src       = (const int*)d_in[3];
    const int*   dst       = (const int*)d_in[4];
    const int*   e2g       = (const int*)d_in[5];
    const int*   n2g       = (const int*)d_in[6];
    const float* We1 = (const float*)d_in[7];  const float* be1 = (const float*)d_in[8];
    const float* We2 = (const float*)d_in[9];  const float* be2 = (const float*)d_in[10];
    const float* We3 = (const float*)d_in[11]; const float* be3 = (const float*)d_in[12];
    const float* Wn1 = (const float*)d_in[13]; const float* bn1 = (const float*)d_in[14];
    const float* Wn2 = (const float*)d_in[15]; const float* bn2 = (const float*)d_in[16];
    const float* Wn3 = (const float*)d_in[17]; const float* bn3 = (const float*)d_in[18];
    const float* Wu1 = (const float*)d_in[19]; const float* bu1 = (const float*)d_in[20];
    const float* Wu2 = (const float*)d_in[21]; const float* bu2 = (const float*)d_in[22];
    const float* Wu3 = (const float*)d_in[23]; const float* bu3 = (const float*)d_in[24];

    const int E = in_sizes[3];   // 400000
    const int N = in_sizes[6];   // 50000

    float* e_out = (float*)d_out;
    float* n_out = e_out + (size_t)E * 64;   // doubles as msgs (overwritten in place)
    float* u_out = n_out + (size_t)N * 64;

    // ws layout (bytes):
    //   0       ecomb_rep  64x1024 f32 (256KB)
    //   262144  ncomb_rep  64x1024 f32 (256KB)
    //   524288  ecomb 1024 f32 | ncomb 1024 f32 (8KB)
    //   532480  bf16 swizzled weights (212992 B)
    char* wsc = (char*)d_ws;
    float* ecomb_rep = (float*)wsc;
    float* ecomb     = (float*)(wsc + 524288);
    float* ncomb     = ecomb + 1024;
    char*  wf        = wsc + 532480;
    const char* We1f = wf;          const char* We2f = wf + 65536;
    const char* We3f = wf + 98304;  const char* Wn1f = wf + 114688;
    const char* Wn2f = wf + 163840; const char* Wn3f = wf + 196608;
    float* ncomb_rep = (float*)(wsc + 262144);

    hipMemsetAsync(n_out, 0, (size_t)N * 64 * sizeof(float), stream);
    hipMemsetAsync(wsc, 0, 524288, stream);

    prep_weights<<<52, 256, 0, stream>>>(We1, We2, We3, Wn1, Wn2, Wn3, wf);

    // 1) edge MLP + msgs scatter + fused e_comb
    mlp_wave_kernel<4, true><<<(E + 63) / 64, 256, 0, stream>>>(
        edge_feat, node_feat, g_repr, src, dst, e2g,
        We1f, be1, We2f, be2, We3f, be3, e_out, n_out, ecomb_rep, E);
    // 2) node MLP (reads msgs from n_out region, overwrites in place) + fused n_comb
    mlp_wave_kernel<3, false><<<(N + 63) / 64, 256, 0, stream>>>(
        node_feat, n_out, g_repr, nullptr, nullptr, n2g,
        Wn1f, bn1, Wn2f, bn2, Wn3f, bn3, n_out, nullptr, ncomb_rep, N);
    // 3) reduce replicas -> ecomb|ncomb
    reduce_rep_kernel<<<8, 256, 0, stream>>>(ecomb_rep, ecomb);
    // 4) global MLP
    u_kernel<<<1, 256, 0, stream>>>(ncomb, ecomb, g_repr,
                                    Wu1, bu1, Wu2, bu2, Wu3, bu3, u_out);
}